// Round 1
// baseline (497.808 us; speedup 1.0000x reference)
//
#include <hip/hip_runtime.h>

#define IN_DIM 128
#define OUT_DIM 64
#define ALPHA 0.2f

// ---------------------------------------------------------------------------
// Kernel 1: M_b = P_b @ W_slice_b, three [128][64] matrices into d_ws.
//   M0 = P_company @ W_PCC[  0: 64]
//   M1 = P_company @ W_PCC[ 64:128]
//   M2 = P_person  @ W_PCC[128:192]
// grid = 48 (3 matrices x 16 chunks), block = 256
// ---------------------------------------------------------------------------
__global__ __launch_bounds__(256) void compute_M_kernel(
    const float* __restrict__ P_company,
    const float* __restrict__ P_person,
    const float* __restrict__ W_PCC,
    float* __restrict__ M)
{
    const int mb = blockIdx.x >> 4;     // which matrix (0,1,2)
    const int chunk = blockIdx.x & 15;  // which 512-entry chunk of 8192
    const float* __restrict__ P = (mb == 2) ? P_person : P_company;
    const float* __restrict__ Wb = W_PCC + mb * OUT_DIM * OUT_DIM;
    float* __restrict__ Mb = M + mb * IN_DIM * OUT_DIM;
    const int base = chunk * 512;
    for (int idx = base + threadIdx.x; idx < base + 512; idx += 256) {
        const int r = idx >> 6;
        const int c = idx & 63;
        float acc = 0.f;
#pragma unroll
        for (int k = 0; k < OUT_DIM; ++k)
            acc = fmaf(P[r * OUT_DIM + k], Wb[k * OUT_DIM + c], acc);
        Mb[idx] = acc;
    }
}

// ---------------------------------------------------------------------------
// Kernel 2: table GEMM  out = feats @ M   ([nrows,128] @ [128,64]).
// lane = row within a 64-row tile; one wave per tile; 4 waves per block.
// NM==2: compute two tables (M0,M1) sharing a single read of feats.
// acc kept in registers; M addresses are wave-uniform (expect s_load).
// ---------------------------------------------------------------------------
template <int NM>
__global__ __launch_bounds__(256) void table_kernel(
    const float* __restrict__ feats, int nrows,
    const float* __restrict__ M0, const float* __restrict__ M1,
    float* __restrict__ out0, float* __restrict__ out1)
{
    const int wave = threadIdx.x >> 6;
    const int lane = threadIdx.x & 63;
    const long long row = ((long long)blockIdx.x * 4 + wave) * 64 + lane;
    const bool valid = row < (long long)nrows;
    const long long lrow = valid ? row : (long long)(nrows - 1);
    const float* __restrict__ x = feats + lrow * IN_DIM;

    float acc0[OUT_DIM];
    float acc1[OUT_DIM];
#pragma unroll
    for (int j = 0; j < OUT_DIM; ++j) { acc0[j] = 0.f; acc1[j] = 0.f; }

    for (int kc = 0; kc < IN_DIM; kc += 16) {
        const float4 xv0 = *(const float4*)(x + kc + 0);
        const float4 xv1 = *(const float4*)(x + kc + 4);
        const float4 xv2 = *(const float4*)(x + kc + 8);
        const float4 xv3 = *(const float4*)(x + kc + 12);
        const float xs[16] = {xv0.x, xv0.y, xv0.z, xv0.w,
                              xv1.x, xv1.y, xv1.z, xv1.w,
                              xv2.x, xv2.y, xv2.z, xv2.w,
                              xv3.x, xv3.y, xv3.z, xv3.w};
#pragma unroll
        for (int kk = 0; kk < 16; ++kk) {
            const float* __restrict__ m0row = M0 + (kc + kk) * OUT_DIM;
#pragma unroll
            for (int j = 0; j < OUT_DIM; j += 4) {
                const float4 m0 = *(const float4*)(m0row + j);
                acc0[j + 0] = fmaf(xs[kk], m0.x, acc0[j + 0]);
                acc0[j + 1] = fmaf(xs[kk], m0.y, acc0[j + 1]);
                acc0[j + 2] = fmaf(xs[kk], m0.z, acc0[j + 2]);
                acc0[j + 3] = fmaf(xs[kk], m0.w, acc0[j + 3]);
            }
            if constexpr (NM == 2) {
                const float* __restrict__ m1row = M1 + (kc + kk) * OUT_DIM;
#pragma unroll
                for (int j = 0; j < OUT_DIM; j += 4) {
                    const float4 m1 = *(const float4*)(m1row + j);
                    acc1[j + 0] = fmaf(xs[kk], m1.x, acc1[j + 0]);
                    acc1[j + 1] = fmaf(xs[kk], m1.y, acc1[j + 1]);
                    acc1[j + 2] = fmaf(xs[kk], m1.z, acc1[j + 2]);
                    acc1[j + 3] = fmaf(xs[kk], m1.w, acc1[j + 3]);
                }
            }
        }
    }

    if (valid) {
        float* __restrict__ o0 = out0 + row * OUT_DIM;
#pragma unroll
        for (int j = 0; j < OUT_DIM; j += 4) {
            *(float4*)(o0 + j) = make_float4(acc0[j], acc0[j + 1], acc0[j + 2], acc0[j + 3]);
        }
        if constexpr (NM == 2) {
            float* __restrict__ o1 = out1 + row * OUT_DIM;
#pragma unroll
            for (int j = 0; j < OUT_DIM; j += 4) {
                *(float4*)(o1 + j) = make_float4(acc1[j], acc1[j + 1], acc1[j + 2], acc1[j + 3]);
            }
        }
    }
}

// ---------------------------------------------------------------------------
// Kernel 3: gather + add + LeakyReLU.
// 16 threads per edge, float4 per thread -> fully coalesced 256B per edge.
// ---------------------------------------------------------------------------
__global__ __launch_bounds__(256) void gather_kernel(
    const int* __restrict__ i0, const int* __restrict__ i1, const int* __restrict__ i2,
    const float* __restrict__ g0, const float* __restrict__ g1, const float* __restrict__ g2,
    float* __restrict__ out, long long E)
{
    const long long t = (long long)blockIdx.x * 256 + threadIdx.x;
    const long long e = t >> 4;
    if (e >= E) return;
    const int sub = ((int)t & 15) << 2;
    const long long r0 = i0[e];
    const long long r1 = i1[e];
    const long long r2 = i2[e];
    const float4 a = *(const float4*)(g0 + r0 * OUT_DIM + sub);
    const float4 b = *(const float4*)(g1 + r1 * OUT_DIM + sub);
    const float4 c = *(const float4*)(g2 + r2 * OUT_DIM + sub);
    float4 p;
    p.x = a.x + b.x + c.x;
    p.y = a.y + b.y + c.y;
    p.z = a.z + b.z + c.z;
    p.w = a.w + b.w + c.w;
    p.x = p.x >= 0.f ? p.x : ALPHA * p.x;
    p.y = p.y >= 0.f ? p.y : ALPHA * p.y;
    p.z = p.z >= 0.f ? p.z : ALPHA * p.z;
    p.w = p.w >= 0.f ? p.w : ALPHA * p.w;
    *(float4*)(out + e * OUT_DIM + sub) = p;
}

// ---------------------------------------------------------------------------
// Fallback (only if ws too small for tables): direct per-edge compute,
// wave per edge, lane = output column, M read from ws (L2-resident).
// ---------------------------------------------------------------------------
__global__ __launch_bounds__(256) void fused_fallback_kernel(
    const float* __restrict__ T, const float* __restrict__ Pp,
    const int* __restrict__ i0, const int* __restrict__ i1, const int* __restrict__ i2,
    const float* __restrict__ M, float* __restrict__ out, long long E)
{
    const int wave = threadIdx.x >> 6;
    const int lane = threadIdx.x & 63;
    const long long wavesTotal = (long long)gridDim.x * 4;
    const float* __restrict__ M0 = M;
    const float* __restrict__ M1 = M + IN_DIM * OUT_DIM;
    const float* __restrict__ M2 = M + 2 * IN_DIM * OUT_DIM;
    for (long long e = (long long)blockIdx.x * 4 + wave; e < E; e += wavesTotal) {
        const float* __restrict__ x0 = T + (long long)i0[e] * IN_DIM;
        const float* __restrict__ x1 = T + (long long)i1[e] * IN_DIM;
        const float* __restrict__ x2 = Pp + (long long)i2[e] * IN_DIM;
        float acc = 0.f;
#pragma unroll 4
        for (int k = 0; k < IN_DIM; ++k) {
            acc = fmaf(x0[k], M0[k * OUT_DIM + lane], acc);
            acc = fmaf(x1[k], M1[k * OUT_DIM + lane], acc);
            acc = fmaf(x2[k], M2[k * OUT_DIM + lane], acc);
        }
        acc = acc >= 0.f ? acc : ALPHA * acc;
        out[e * OUT_DIM + lane] = acc;
    }
}

// ---------------------------------------------------------------------------
extern "C" void kernel_launch(void* const* d_in, const int* in_sizes, int n_in,
                              void* d_out, int out_size, void* d_ws, size_t ws_size,
                              hipStream_t stream) {
    const float* T    = (const float*)d_in[0];  // taxPayer_feats [N_C,128]
    const float* Pp   = (const float*)d_in[1];  // person_feats   [N_P,128]
    // d_in[2] item_feats: unused for PCC
    const int*   i0   = (const int*)d_in[3];
    const int*   i1   = (const int*)d_in[4];
    const int*   i2   = (const int*)d_in[5];
    const float* Pc   = (const float*)d_in[6];  // P_company [128,64]
    const float* Pper = (const float*)d_in[7];  // P_person  [128,64]
    const float* W    = (const float*)d_in[9];  // W_PCC     [192,64]
    float* out = (float*)d_out;

    const int n_c = in_sizes[0] / IN_DIM;
    const int n_p = in_sizes[1] / IN_DIM;
    const long long E = in_sizes[3];

    float* M = (float*)d_ws;
    const size_t needM = (size_t)3 * IN_DIM * OUT_DIM * sizeof(float);
    const size_t tblBytes = ((size_t)n_c * 2 + (size_t)n_p) * OUT_DIM * sizeof(float);

    // 1) fused projection matrices
    compute_M_kernel<<<48, 256, 0, stream>>>(Pc, Pper, W, M);

    if (ws_size >= needM + tblBytes) {
        float* g0 = M + 3 * IN_DIM * OUT_DIM;
        float* g1 = g0 + (size_t)n_c * OUT_DIM;
        float* g2 = g1 + (size_t)n_c * OUT_DIM;

        // 2) tables: g0/g1 from taxPayer (one read of T), g2 from person
        table_kernel<2><<<(n_c + 255) / 256, 256, 0, stream>>>(
            T, n_c, M, M + IN_DIM * OUT_DIM, g0, g1);
        table_kernel<1><<<(n_p + 255) / 256, 256, 0, stream>>>(
            Pp, n_p, M + 2 * IN_DIM * OUT_DIM, nullptr, g2, nullptr);

        // 3) gather + add + LeakyReLU
        const long long threads = E * 16;
        gather_kernel<<<(int)((threads + 255) / 256), 256, 0, stream>>>(
            i0, i1, i2, g0, g1, g2, out, E);
    } else {
        fused_fallback_kernel<<<16384, 256, 0, stream>>>(T, Pp, i0, i1, i2, M, out, E);
    }
}